// Round 5
// baseline (1099.172 us; speedup 1.0000x reference)
//
#include <hip/hip_runtime.h>
#include <hip/hip_bf16.h>
#include <cstdint>
#include <cstddef>

// out = (A2 @ E^T) @ W^T, A2[i,j] = a[i-j] lower-tri Toeplitz,
//   a[d] = (d/4096 + 1e-8)^0.2, a[0] = 1e-8^0.2
// gemm_a: T[i,e] = sum_{j<=i} a[i-j] * E[e,j]  (tri, split-j -> T0 + T1)
// gemm_b: out[i,v] = sum_e (T0+T1)[i,e] * W[v,e]
// Round 5: prefetch distance 2 (each global load gets ~2 K-steps to land),
// ping-pong LDS, one barrier/step; gemm_b 64x128 (512 blocks, 2/CU); fused prep.

#define L_SER 4096
#define DEMB  1024
#define DV    1024

#define R_STRIDE 4224   // shift-replica stride of reversed a; 16B-aligned
#define R_O0     4096
#define LDP      72     // padded LDS row (elems): uniform bank groups on b128

typedef __bf16 bf16_t;
typedef __attribute__((ext_vector_type(8))) __bf16 bf16x8;
typedef __attribute__((ext_vector_type(4))) float f32x4;

// ---------------------------------------------------------------------------
// Fused prep: blocks [0,132) build R; [132,2180) convert E; [2180,2692) convert W.
// ---------------------------------------------------------------------------
__global__ void prep_kernel(const float* __restrict__ E, const float* __restrict__ W,
                            bf16_t* __restrict__ Eb, bf16_t* __restrict__ Wb,
                            bf16_t* __restrict__ R) {
    const int b = blockIdx.x;
    if (b < 132) {                       // 132*256 = 33792 = 8*4224 exact
        int idx = b * 256 + threadIdx.x;
        int s = idx / R_STRIDE;
        int x = idx - s * R_STRIDE;
        int d = R_O0 + s - x;
        float v = 0.0f;
        if (d >= 0 && d < L_SER)
            v = powf((d == 0) ? 1e-8f : ((float)d * (1.0f / (float)L_SER) + 1e-8f), 0.2f);
        R[idx] = (bf16_t)v;
    } else if (b < 132 + 2048) {         // E: 2048*256*8 = 4194304 elems exact
        int idx = (b - 132) * 256 + threadIdx.x;
        const f32x4* s = (const f32x4*)E;
        f32x4 v0 = s[idx * 2], v1 = s[idx * 2 + 1];
        bf16x8 o;
        o[0] = (bf16_t)v0[0]; o[1] = (bf16_t)v0[1]; o[2] = (bf16_t)v0[2]; o[3] = (bf16_t)v0[3];
        o[4] = (bf16_t)v1[0]; o[5] = (bf16_t)v1[1]; o[6] = (bf16_t)v1[2]; o[7] = (bf16_t)v1[3];
        ((bf16x8*)Eb)[idx] = o;
    } else {                             // W: 512*256*8 = 1048576 elems exact
        int idx = (b - 2180) * 256 + threadIdx.x;
        const f32x4* s = (const f32x4*)W;
        f32x4 v0 = s[idx * 2], v1 = s[idx * 2 + 1];
        bf16x8 o;
        o[0] = (bf16_t)v0[0]; o[1] = (bf16_t)v0[1]; o[2] = (bf16_t)v0[2]; o[3] = (bf16_t)v0[3];
        o[4] = (bf16_t)v1[0]; o[5] = (bf16_t)v1[1]; o[6] = (bf16_t)v1[2]; o[7] = (bf16_t)v1[3];
        ((bf16x8*)Wb)[idx] = o;
    }
}

// ---------------------------------------------------------------------------
// gemm_a: BM=128, BN=128, BK=64, split-j. 512 blocks all co-resident (2/CU);
// pair (bid, bid+256) shares a CU -> per-CU work = I+1 + 32-I = 33 steps.
// Distance-2 register prefetch: at step s, load s+2; ds_write consumes loads
// issued two steps earlier (fully landed).
// ---------------------------------------------------------------------------
__global__ __launch_bounds__(256) void gemm_a_kernel(const bf16_t* __restrict__ R,
                                                     const bf16_t* __restrict__ Eb,
                                                     bf16_t* __restrict__ T0,
                                                     bf16_t* __restrict__ T1) {
    __shared__ __align__(16) bf16_t sA[2 * 128 * LDP];   // 36 KB
    __shared__ __align__(16) bf16_t sB[2 * 128 * LDP];   // 36 KB

    const int bid = blockIdx.x;
    int I, nb, h;
    if (bid < 256) { I = bid >> 3;                nb = bid & 7;         h = 0; }
    else           { I = 31 - ((bid - 256) >> 3); nb = (bid - 256) & 7; h = 1; }
    const int i0 = I * 128;
    const int n0 = nb * 128;
    const int nsteps = I + 1;
    const int j0b = h ? 64 * (I + 1) : 0;
    bf16_t* __restrict__ Tout = h ? T1 : T0;

    const int tid  = threadIdx.x;
    const int wave = tid >> 6;
    const int lane = tid & 63;
    const int quad = lane >> 4;
    const int ln   = lane & 15;
    const int wm   = wave >> 1;
    const int wn   = wave & 1;
    const int srow = tid >> 3;              // 0..31
    const int kc8  = (tid & 7) * 8;

    f32x4 acc[4][4];
#pragma unroll
    for (int a = 0; a < 4; ++a)
#pragma unroll
        for (int b = 0; b < 4; ++b) acc[a][b] = (f32x4){0, 0, 0, 0};

    const bf16_t* pA[4];
    const bf16_t* pB[4];
    bf16x8 ra[2][4], rb[2][4];
#pragma unroll
    for (int c = 0; c < 4; ++c) {
        int r = c * 32 + srow;
        pA[c] = R + (size_t)(r & 7) * R_STRIDE + (R_O0 - i0 + j0b - 8 * (r >> 3) + kc8);
        pB[c] = Eb + (size_t)(n0 + c * 32 + srow) * L_SER + j0b + kc8;
        ra[0][c] = *(const bf16x8*)pA[c];
        rb[0][c] = *(const bf16x8*)pB[c];
        pA[c] += 64; pB[c] += 64;
    }
    if (nsteps > 1) {
#pragma unroll
        for (int c = 0; c < 4; ++c) {
            ra[1][c] = *(const bf16x8*)pA[c];
            rb[1][c] = *(const bf16x8*)pB[c];
            pA[c] += 64; pB[c] += 64;
        }
    }

    for (int step = 0; step < nsteps; ++step) {
        const int cur = step & 1;
        const int sb = cur * 128 * LDP;
#pragma unroll
        for (int c = 0; c < 4; ++c) {
            *(bf16x8*)&sA[sb + (c * 32 + srow) * LDP + kc8] = ra[cur][c];
            *(bf16x8*)&sB[sb + (c * 32 + srow) * LDP + kc8] = rb[cur][c];
        }
        __syncthreads();

        if (step + 2 < nsteps) {
#pragma unroll
            for (int c = 0; c < 4; ++c) {
                ra[cur][c] = *(const bf16x8*)pA[c];
                rb[cur][c] = *(const bf16x8*)pB[c];
                pA[c] += 64; pB[c] += 64;
            }
        }

#pragma unroll
        for (int kk = 0; kk < 2; ++kk) {
            bf16x8 afr[4], bfr[4];
#pragma unroll
            for (int tm = 0; tm < 4; ++tm)
                afr[tm] = *(const bf16x8*)&sA[sb + (wm * 64 + tm * 16 + ln) * LDP + kk * 32 + quad * 8];
#pragma unroll
            for (int tn = 0; tn < 4; ++tn)
                bfr[tn] = *(const bf16x8*)&sB[sb + (wn * 64 + tn * 16 + ln) * LDP + kk * 32 + quad * 8];
#pragma unroll
            for (int tm = 0; tm < 4; ++tm)
#pragma unroll
                for (int tn = 0; tn < 4; ++tn)
                    acc[tm][tn] = __builtin_amdgcn_mfma_f32_16x16x32_bf16(afr[tm], bfr[tn], acc[tm][tn], 0, 0, 0);
        }
    }

    // C/D: col = ln, row = quad*4 + r (m89-verified)
#pragma unroll
    for (int tm = 0; tm < 4; ++tm) {
        int row_base = i0 + wm * 64 + tm * 16 + quad * 4;
#pragma unroll
        for (int tn = 0; tn < 4; ++tn) {
            int col = n0 + wn * 64 + tn * 16 + ln;
#pragma unroll
            for (int r = 0; r < 4; ++r)
                Tout[(size_t)(row_base + r) * DEMB + col] = (bf16_t)acc[tm][tn][r];
        }
    }
}

// ---------------------------------------------------------------------------
// gemm_b: out[i,v] = sum_e (T0+T1)[i,e] * W[v,e]. BM=64, BN=128, BK=64.
// 512 blocks (2/CU). T0+T1 added in registers during prefetch (distance 2).
// ---------------------------------------------------------------------------
__global__ __launch_bounds__(256) void gemm_b_kernel(const bf16_t* __restrict__ T0,
                                                     const bf16_t* __restrict__ T1,
                                                     const bf16_t* __restrict__ Wb,
                                                     float* __restrict__ out) {
    __shared__ __align__(16) bf16_t sA[2 * 64 * LDP];    // 18 KB
    __shared__ __align__(16) bf16_t sB[2 * 128 * LDP];   // 36 KB

    const int bid = blockIdx.x;
    const int ib = bid >> 3;        // 0..63
    const int nb = bid & 7;         // same-nb blocks co-XCD -> Wb slice L2-resident
    const int i0 = ib * 64;
    const int n0 = nb * 128;

    const int tid  = threadIdx.x;
    const int wave = tid >> 6;
    const int lane = tid & 63;
    const int quad = lane >> 4;
    const int ln   = lane & 15;
    const int wm   = wave >> 1;     // 0..1 over 64 m
    const int wn   = wave & 1;      // 0..1 over 128 n
    const int srow = tid >> 3;      // 0..31
    const int kc8  = (tid & 7) * 8;

    f32x4 acc[2][4];
#pragma unroll
    for (int a = 0; a < 2; ++a)
#pragma unroll
        for (int b = 0; b < 4; ++b) acc[a][b] = (f32x4){0, 0, 0, 0};

    const int nsteps = DEMB / 64;   // 16

    const bf16_t* p0[2];
    const bf16_t* p1[2];
    const bf16_t* pW[4];
    bf16x8 ra[2][2], rb[2][4];
#pragma unroll
    for (int c = 0; c < 2; ++c) {
        size_t arow = (size_t)(i0 + c * 32 + srow) * DEMB + kc8;
        p0[c] = T0 + arow;
        p1[c] = T1 + arow;
    }
#pragma unroll
    for (int c = 0; c < 4; ++c)
        pW[c] = Wb + (size_t)(n0 + c * 32 + srow) * DEMB + kc8;

#pragma unroll
    for (int d = 0; d < 2; ++d) {   // preload steps 0 and 1
#pragma unroll
        for (int c = 0; c < 2; ++c) {
            bf16x8 t0 = *(const bf16x8*)p0[c];
            bf16x8 t1 = *(const bf16x8*)p1[c];
            bf16x8 o;
#pragma unroll
            for (int u = 0; u < 8; ++u) o[u] = (bf16_t)((float)t0[u] + (float)t1[u]);
            ra[d][c] = o;
            p0[c] += 64; p1[c] += 64;
        }
#pragma unroll
        for (int c = 0; c < 4; ++c) {
            rb[d][c] = *(const bf16x8*)pW[c];
            pW[c] += 64;
        }
    }

    for (int step = 0; step < nsteps; ++step) {
        const int cur = step & 1;
        const int sba = cur * 64 * LDP;
        const int sbb = cur * 128 * LDP;
#pragma unroll
        for (int c = 0; c < 2; ++c)
            *(bf16x8*)&sA[sba + (c * 32 + srow) * LDP + kc8] = ra[cur][c];
#pragma unroll
        for (int c = 0; c < 4; ++c)
            *(bf16x8*)&sB[sbb + (c * 32 + srow) * LDP + kc8] = rb[cur][c];
        __syncthreads();

        if (step + 2 < nsteps) {
#pragma unroll
            for (int c = 0; c < 2; ++c) {
                bf16x8 t0 = *(const bf16x8*)p0[c];
                bf16x8 t1 = *(const bf16x8*)p1[c];
                bf16x8 o;
#pragma unroll
                for (int u = 0; u < 8; ++u) o[u] = (bf16_t)((float)t0[u] + (float)t1[u]);
                ra[cur][c] = o;
                p0[c] += 64; p1[c] += 64;
            }
#pragma unroll
            for (int c = 0; c < 4; ++c) {
                rb[cur][c] = *(const bf16x8*)pW[c];
                pW[c] += 64;
            }
        }

#pragma unroll
        for (int kk = 0; kk < 2; ++kk) {
            bf16x8 afr[2], bfr[4];
#pragma unroll
            for (int tm = 0; tm < 2; ++tm)
                afr[tm] = *(const bf16x8*)&sA[sba + (wm * 32 + tm * 16 + ln) * LDP + kk * 32 + quad * 8];
#pragma unroll
            for (int tn = 0; tn < 4; ++tn)
                bfr[tn] = *(const bf16x8*)&sB[sbb + (wn * 64 + tn * 16 + ln) * LDP + kk * 32 + quad * 8];
#pragma unroll
            for (int tm = 0; tm < 2; ++tm)
#pragma unroll
                for (int tn = 0; tn < 4; ++tn)
                    acc[tm][tn] = __builtin_amdgcn_mfma_f32_16x16x32_bf16(afr[tm], bfr[tn], acc[tm][tn], 0, 0, 0);
        }
    }

#pragma unroll
    for (int tm = 0; tm < 2; ++tm) {
        int row_base = i0 + wm * 32 + tm * 16 + quad * 4;
#pragma unroll
        for (int tn = 0; tn < 4; ++tn) {
            int col = n0 + wn * 64 + tn * 16 + ln;
#pragma unroll
            for (int r = 0; r < 4; ++r)
                out[(size_t)(row_base + r) * DV + col] = acc[tm][tn][r];
        }
    }
}

// ---------------------------------------------------------------------------
extern "C" void kernel_launch(void* const* d_in, const int* in_sizes, int n_in,
                              void* d_out, int out_size, void* d_ws, size_t ws_size,
                              hipStream_t stream) {
    const float* E = (const float*)d_in[0];   // (1024, 4096) f32
    const float* W = (const float*)d_in[1];   // (1024, 1024) f32
    float* out = (float*)d_out;               // (4096, 1024) f32

    char* ws = (char*)d_ws;
    bf16_t* Eb = (bf16_t*)(ws);                               // 8 MB
    bf16_t* T0 = (bf16_t*)(ws + (size_t)8  * 1024 * 1024);    // 8 MB
    bf16_t* T1 = (bf16_t*)(ws + (size_t)16 * 1024 * 1024);    // 8 MB
    bf16_t* Wb = (bf16_t*)(ws + (size_t)24 * 1024 * 1024);    // 2 MB
    bf16_t* R  = (bf16_t*)(ws + (size_t)26 * 1024 * 1024);    // 66 KB

    prep_kernel<<<2692, 256, 0, stream>>>(E, W, Eb, Wb, R);
    gemm_a_kernel<<<512, 256, 0, stream>>>(R, Eb, T0, T1);
    gemm_b_kernel<<<512, 256, 0, stream>>>(T0, T1, Wb, out);
}

// Round 6
// 133.201 us; speedup vs baseline: 8.2520x; 8.2520x over previous
//
#include <hip/hip_runtime.h>
#include <hip/hip_bf16.h>
#include <cstdint>
#include <cstddef>

// out = (A2 @ E^T) @ W^T, A2[i,j] = a[i-j] lower-tri Toeplitz,
//   a[d] = (d/4096 + 1e-8)^0.2, a[0] = 1e-8^0.2
// gemm_a: T[i,e] = sum_{j<=i} a[i-j] * E[e,j]  (tri, split-j -> T0 + T1)
// gemm_b: out[i,v] = sum_e (T0+T1)[i,e] * W[v,e]
// Round 6: R5's distance-2 pipeline had dynamically-indexed prefetch arrays
// (ra[cur][c]) -> scratch spill -> 16x regression. Fixed: 2x-unrolled K-loop
// with STATIC register sets + static LDS buffer offsets; __launch_bounds__(256,2)
// raises VGPR cap to 256 (2 blocks/CU is the LDS ceiling anyway).

#define L_SER 4096
#define DEMB  1024
#define DV    1024

#define R_STRIDE 4224   // shift-replica stride of reversed a; 16B-aligned
#define R_O0     4096
#define LDP      72     // padded LDS row (elems): uniform bank groups on b128

typedef __bf16 bf16_t;
typedef __attribute__((ext_vector_type(8))) __bf16 bf16x8;
typedef __attribute__((ext_vector_type(4))) float f32x4;

// ---------------------------------------------------------------------------
// Fused prep: blocks [0,132) build R; [132,2180) convert E; [2180,2692) convert W.
// ---------------------------------------------------------------------------
__global__ void prep_kernel(const float* __restrict__ E, const float* __restrict__ W,
                            bf16_t* __restrict__ Eb, bf16_t* __restrict__ Wb,
                            bf16_t* __restrict__ R) {
    const int b = blockIdx.x;
    if (b < 132) {                       // 132*256 = 33792 = 8*4224 exact
        int idx = b * 256 + threadIdx.x;
        int s = idx / R_STRIDE;
        int x = idx - s * R_STRIDE;
        int d = R_O0 + s - x;
        float v = 0.0f;
        if (d >= 0 && d < L_SER)
            v = powf((d == 0) ? 1e-8f : ((float)d * (1.0f / (float)L_SER) + 1e-8f), 0.2f);
        R[idx] = (bf16_t)v;
    } else if (b < 132 + 2048) {         // E: 2048*256*8 = 4194304 elems exact
        int idx = (b - 132) * 256 + threadIdx.x;
        const f32x4* s = (const f32x4*)E;
        f32x4 v0 = s[idx * 2], v1 = s[idx * 2 + 1];
        bf16x8 o;
        o[0] = (bf16_t)v0[0]; o[1] = (bf16_t)v0[1]; o[2] = (bf16_t)v0[2]; o[3] = (bf16_t)v0[3];
        o[4] = (bf16_t)v1[0]; o[5] = (bf16_t)v1[1]; o[6] = (bf16_t)v1[2]; o[7] = (bf16_t)v1[3];
        ((bf16x8*)Eb)[idx] = o;
    } else {                             // W: 512*256*8 = 1048576 elems exact
        int idx = (b - 2180) * 256 + threadIdx.x;
        const f32x4* s = (const f32x4*)W;
        f32x4 v0 = s[idx * 2], v1 = s[idx * 2 + 1];
        bf16x8 o;
        o[0] = (bf16_t)v0[0]; o[1] = (bf16_t)v0[1]; o[2] = (bf16_t)v0[2]; o[3] = (bf16_t)v0[3];
        o[4] = (bf16_t)v1[0]; o[5] = (bf16_t)v1[1]; o[6] = (bf16_t)v1[2]; o[7] = (bf16_t)v1[3];
        ((bf16x8*)Wb)[idx] = o;
    }
}

// ---------------------------------------------------------------------------
// gemm_a: BM=128, BN=128, BK=64, split-j. 512 blocks (2/CU); pair (bid,bid+256)
// shares a CU -> per-CU work = (I+1) + (32-I) = 33 steps. Distance-2 prefetch,
// static ping-pong register sets and LDS buffers, one barrier per K-step.
// ---------------------------------------------------------------------------
#define GA_STAGE(SBOFS, RA, RB)                                              \
    _Pragma("unroll")                                                        \
    for (int c = 0; c < 4; ++c) {                                            \
        *(bf16x8*)&sA[(SBOFS) + (c * 32 + srow) * LDP + kc8] = RA[c];        \
        *(bf16x8*)&sB[(SBOFS) + (c * 32 + srow) * LDP + kc8] = RB[c];        \
    }

#define GA_PREFETCH(RA, RB)                                                  \
    _Pragma("unroll")                                                        \
    for (int c = 0; c < 4; ++c) {                                            \
        RA[c] = *(const bf16x8*)pA[c];                                       \
        RB[c] = *(const bf16x8*)pB[c];                                       \
        pA[c] += 64; pB[c] += 64;                                            \
    }

#define GA_COMPUTE(SBOFS)                                                    \
    _Pragma("unroll")                                                        \
    for (int kk = 0; kk < 2; ++kk) {                                         \
        bf16x8 afr[4], bfr[4];                                               \
        _Pragma("unroll")                                                    \
        for (int tm = 0; tm < 4; ++tm)                                       \
            afr[tm] = *(const bf16x8*)&sA[(SBOFS) + (wm * 64 + tm * 16 + ln) * LDP + kk * 32 + quad * 8]; \
        _Pragma("unroll")                                                    \
        for (int tn = 0; tn < 4; ++tn)                                       \
            bfr[tn] = *(const bf16x8*)&sB[(SBOFS) + (wn * 64 + tn * 16 + ln) * LDP + kk * 32 + quad * 8]; \
        _Pragma("unroll")                                                    \
        for (int tm = 0; tm < 4; ++tm)                                       \
            _Pragma("unroll")                                                \
            for (int tn = 0; tn < 4; ++tn)                                   \
                acc[tm][tn] = __builtin_amdgcn_mfma_f32_16x16x32_bf16(afr[tm], bfr[tn], acc[tm][tn], 0, 0, 0); \
    }

__global__ __launch_bounds__(256, 2) void gemm_a_kernel(const bf16_t* __restrict__ R,
                                                        const bf16_t* __restrict__ Eb,
                                                        bf16_t* __restrict__ T0,
                                                        bf16_t* __restrict__ T1) {
    __shared__ __align__(16) bf16_t sA[2 * 128 * LDP];   // 36 KB
    __shared__ __align__(16) bf16_t sB[2 * 128 * LDP];   // 36 KB

    const int bid = blockIdx.x;
    int I, nb, h;
    if (bid < 256) { I = bid >> 3;                nb = bid & 7;         h = 0; }
    else           { I = 31 - ((bid - 256) >> 3); nb = (bid - 256) & 7; h = 1; }
    const int i0 = I * 128;
    const int n0 = nb * 128;
    const int nsteps = I + 1;
    const int j0b = h ? 64 * (I + 1) : 0;
    bf16_t* __restrict__ Tout = h ? T1 : T0;

    const int tid  = threadIdx.x;
    const int wave = tid >> 6;
    const int lane = tid & 63;
    const int quad = lane >> 4;
    const int ln   = lane & 15;
    const int wm   = wave >> 1;
    const int wn   = wave & 1;
    const int srow = tid >> 3;              // 0..31
    const int kc8  = (tid & 7) * 8;

    f32x4 acc[4][4];
#pragma unroll
    for (int a = 0; a < 4; ++a)
#pragma unroll
        for (int b = 0; b < 4; ++b) acc[a][b] = (f32x4){0, 0, 0, 0};

    // A row r: replica s=r&7, back-off 8*(r>>3):
    //   elem (r, col) at step j0 = R[s][R_O0 - (i0-j0) - 8*(r>>3) + col]
    const bf16_t* pA[4];
    const bf16_t* pB[4];
    bf16x8 ra0[4], rb0[4], ra1[4], rb1[4];
#pragma unroll
    for (int c = 0; c < 4; ++c) {
        int r = c * 32 + srow;
        pA[c] = R + (size_t)(r & 7) * R_STRIDE + (R_O0 - i0 + j0b - 8 * (r >> 3) + kc8);
        pB[c] = Eb + (size_t)(n0 + c * 32 + srow) * L_SER + j0b + kc8;
    }
    GA_PREFETCH(ra0, rb0)                       // step 0
    if (nsteps > 1) { GA_PREFETCH(ra1, rb1) }   // step 1

    for (int s = 0;; s += 2) {
        // ---- phase 0: step s (buffer 0, set 0) ----
        GA_STAGE(0, ra0, rb0)
        __syncthreads();
        if (s + 2 < nsteps) { GA_PREFETCH(ra0, rb0) }
        GA_COMPUTE(0)
        if (s + 1 >= nsteps) break;
        // ---- phase 1: step s+1 (buffer 1, set 1) ----
        GA_STAGE(128 * LDP, ra1, rb1)
        __syncthreads();
        if (s + 3 < nsteps) { GA_PREFETCH(ra1, rb1) }
        GA_COMPUTE(128 * LDP)
        if (s + 2 >= nsteps) break;
    }

    // C/D: col = ln, row = quad*4 + r (m89-verified)
#pragma unroll
    for (int tm = 0; tm < 4; ++tm) {
        int row_base = i0 + wm * 64 + tm * 16 + quad * 4;
#pragma unroll
        for (int tn = 0; tn < 4; ++tn) {
            int col = n0 + wn * 64 + tn * 16 + ln;
#pragma unroll
            for (int r = 0; r < 4; ++r)
                Tout[(size_t)(row_base + r) * DEMB + col] = (bf16_t)acc[tm][tn][r];
        }
    }
}

// ---------------------------------------------------------------------------
// gemm_b: out[i,v] = sum_e (T0+T1)[i,e] * W[v,e]. BM=64, BN=128, BK=64, K=1024.
// 512 blocks (2/CU). Static ping-pong register sets; T0+T1 added in registers.
// ---------------------------------------------------------------------------
#define GB_STAGE(SBOFS_A, SBOFS_B, RA, RB)                                   \
    _Pragma("unroll")                                                        \
    for (int c = 0; c < 2; ++c)                                              \
        *(bf16x8*)&sA[(SBOFS_A) + (c * 32 + srow) * LDP + kc8] = RA[c];      \
    _Pragma("unroll")                                                        \
    for (int c = 0; c < 4; ++c)                                              \
        *(bf16x8*)&sB[(SBOFS_B) + (c * 32 + srow) * LDP + kc8] = RB[c];

#define GB_PREFETCH(RA, RB)                                                  \
    _Pragma("unroll")                                                        \
    for (int c = 0; c < 2; ++c) {                                            \
        bf16x8 t0 = *(const bf16x8*)p0[c];                                   \
        bf16x8 t1 = *(const bf16x8*)p1[c];                                   \
        bf16x8 o;                                                            \
        _Pragma("unroll")                                                    \
        for (int u = 0; u < 8; ++u) o[u] = (bf16_t)((float)t0[u] + (float)t1[u]); \
        RA[c] = o;                                                           \
        p0[c] += 64; p1[c] += 64;                                            \
    }                                                                        \
    _Pragma("unroll")                                                        \
    for (int c = 0; c < 4; ++c) {                                            \
        RB[c] = *(const bf16x8*)pW[c];                                       \
        pW[c] += 64;                                                         \
    }

#define GB_COMPUTE(SBOFS_A, SBOFS_B)                                         \
    _Pragma("unroll")                                                        \
    for (int kk = 0; kk < 2; ++kk) {                                         \
        bf16x8 afr[2], bfr[4];                                               \
        _Pragma("unroll")                                                    \
        for (int tm = 0; tm < 2; ++tm)                                       \
            afr[tm] = *(const bf16x8*)&sA[(SBOFS_A) + (wm * 32 + tm * 16 + ln) * LDP + kk * 32 + quad * 8]; \
        _Pragma("unroll")                                                    \
        for (int tn = 0; tn < 4; ++tn)                                       \
            bfr[tn] = *(const bf16x8*)&sB[(SBOFS_B) + (wn * 64 + tn * 16 + ln) * LDP + kk * 32 + quad * 8]; \
        _Pragma("unroll")                                                    \
        for (int tm = 0; tm < 2; ++tm)                                       \
            _Pragma("unroll")                                                \
            for (int tn = 0; tn < 4; ++tn)                                   \
                acc[tm][tn] = __builtin_amdgcn_mfma_f32_16x16x32_bf16(afr[tm], bfr[tn], acc[tm][tn], 0, 0, 0); \
    }

__global__ __launch_bounds__(256, 2) void gemm_b_kernel(const bf16_t* __restrict__ T0,
                                                        const bf16_t* __restrict__ T1,
                                                        const bf16_t* __restrict__ Wb,
                                                        float* __restrict__ out) {
    __shared__ __align__(16) bf16_t sA[2 * 64 * LDP];    // 18 KB
    __shared__ __align__(16) bf16_t sB[2 * 128 * LDP];   // 36 KB

    const int bid = blockIdx.x;
    const int ib = bid >> 3;        // 0..63
    const int nb = bid & 7;
    const int i0 = ib * 64;
    const int n0 = nb * 128;

    const int tid  = threadIdx.x;
    const int wave = tid >> 6;
    const int lane = tid & 63;
    const int quad = lane >> 4;
    const int ln   = lane & 15;
    const int wm   = wave >> 1;     // 0..1 over 64 m
    const int wn   = wave & 1;      // 0..1 over 128 n
    const int srow = tid >> 3;      // 0..31
    const int kc8  = (tid & 7) * 8;

    f32x4 acc[2][4];
#pragma unroll
    for (int a = 0; a < 2; ++a)
#pragma unroll
        for (int b = 0; b < 4; ++b) acc[a][b] = (f32x4){0, 0, 0, 0};

    const int nsteps = DEMB / 64;   // 16 (even)

    const bf16_t* p0[2];
    const bf16_t* p1[2];
    const bf16_t* pW[4];
    bf16x8 ra0[2], rb0[4], ra1[2], rb1[4];
#pragma unroll
    for (int c = 0; c < 2; ++c) {
        size_t arow = (size_t)(i0 + c * 32 + srow) * DEMB + kc8;
        p0[c] = T0 + arow;
        p1[c] = T1 + arow;
    }
#pragma unroll
    for (int c = 0; c < 4; ++c)
        pW[c] = Wb + (size_t)(n0 + c * 32 + srow) * DEMB + kc8;

    GB_PREFETCH(ra0, rb0)   // step 0
    GB_PREFETCH(ra1, rb1)   // step 1

    for (int s = 0;; s += 2) {
        GB_STAGE(0, 0, ra0, rb0)
        __syncthreads();
        if (s + 2 < nsteps) { GB_PREFETCH(ra0, rb0) }
        GB_COMPUTE(0, 0)
        // nsteps even: no break needed after phase 0
        GB_STAGE(64 * LDP, 128 * LDP, ra1, rb1)
        __syncthreads();
        if (s + 3 < nsteps) { GB_PREFETCH(ra1, rb1) }
        GB_COMPUTE(64 * LDP, 128 * LDP)
        if (s + 2 >= nsteps) break;
    }

#pragma unroll
    for (int tm = 0; tm < 2; ++tm) {
        int row_base = i0 + wm * 32 + tm * 16 + quad * 4;
#pragma unroll
        for (int tn = 0; tn < 4; ++tn) {
            int col = n0 + wn * 64 + tn * 16 + ln;
#pragma unroll
            for (int r = 0; r < 4; ++r)
                out[(size_t)(row_base + r) * DV + col] = acc[tm][tn][r];
        }
    }
}

// ---------------------------------------------------------------------------
extern "C" void kernel_launch(void* const* d_in, const int* in_sizes, int n_in,
                              void* d_out, int out_size, void* d_ws, size_t ws_size,
                              hipStream_t stream) {
    const float* E = (const float*)d_in[0];   // (1024, 4096) f32
    const float* W = (const float*)d_in[1];   // (1024, 1024) f32
    float* out = (float*)d_out;               // (4096, 1024) f32

    char* ws = (char*)d_ws;
    bf16_t* Eb = (bf16_t*)(ws);                               // 8 MB
    bf16_t* T0 = (bf16_t*)(ws + (size_t)8  * 1024 * 1024);    // 8 MB
    bf16_t* T1 = (bf16_t*)(ws + (size_t)16 * 1024 * 1024);    // 8 MB
    bf16_t* Wb = (bf16_t*)(ws + (size_t)24 * 1024 * 1024);    // 2 MB
    bf16_t* R  = (bf16_t*)(ws + (size_t)26 * 1024 * 1024);    // 66 KB

    prep_kernel<<<2692, 256, 0, stream>>>(E, W, Eb, Wb, R);
    gemm_a_kernel<<<512, 256, 0, stream>>>(R, Eb, T0, T1);
    gemm_b_kernel<<<512, 256, 0, stream>>>(T0, T1, Wb, out);
}